// Round 18
// baseline (329.215 us; speedup 1.0000x reference)
//
#include <hip/hip_runtime.h>
#include <hip/hip_fp16.h>

#define NB 64
#define NSP 784
#define CDIM 512
#define CQK 256
#define C4 128
#define NHEADS 8
#define CCAT 1024
#define BN_EPS 1e-5f
#define ATT_SCALE 0.17677669529663687f  // 32^-0.5

using half8_t = __attribute__((ext_vector_type(8))) _Float16;
using half4_t = __attribute__((ext_vector_type(4))) _Float16;
using half2_t = __attribute__((ext_vector_type(2))) _Float16;
using f32x4_t = __attribute__((ext_vector_type(4))) float;

__device__ __forceinline__ void bn_coef(const float* bn, int cout, int o, float& inv, float& add) {
    float g = bn[o], be = bn[cout + o], m = bn[2 * cout + o], v = bn[3 * cout + o];
    inv = g * rsqrtf(v + BN_EPS);
    add = be - m * inv;
}

__device__ __forceinline__ float fdot2(half2_t a, half2_t b, float c) {
#if __has_builtin(__builtin_amdgcn_fdot2)
    return __builtin_amdgcn_fdot2(a, b, c, false);
#else
    return c + (float)a[0] * (float)b[0] + (float)a[1] * (float)b[1];
#endif
}

// async global->LDS, 16B per lane; LDS dest must be wave-linear (base + lane*16).
__device__ __forceinline__ void gload16(const void* g, void* l) {
    __builtin_amdgcn_global_load_lds(
        (const __attribute__((address_space(1))) void*)g,
        (__attribute__((address_space(3))) void*)l, 16, 0, 0);
}

// ---- prep: merged x-transpose (blocks 0..1023) + weight convert (blocks 1024..1727) ----
__global__ __launch_bounds__(256)
void prep_kernel(const float* __restrict__ x, _Float16* __restrict__ xt,
                 const float* __restrict__ qk, const float* __restrict__ vs,
                 const float* __restrict__ pj, _Float16* __restrict__ wdst)
{
    __shared__ _Float16 t2[392][66];
    const int idx = blockIdx.x;
    if (idx < 1024) {
        const int c0 = (idx & 7) * 64, sp0 = ((idx >> 3) & 1) * 392, b = idx >> 4;
        const float* src = x + ((long)b * CDIM + c0) * NSP + sp0;
        for (int i = threadIdx.x; i < 64 * 392; i += 256) {
            const int c = i / 392, sp = i - c * 392;
            t2[sp][c] = (_Float16)src[(long)c * NSP + sp];
        }
        __syncthreads();
        _Float16* dst = xt + ((long)b * NSP + sp0) * CDIM + c0;
        for (int i = threadIdx.x; i < 392 * 8; i += 256) {
            const int sp = i >> 3, cg = i & 7;
            *(half8_t*)(dst + (long)sp * CDIM + cg * 8) = *(const half8_t*)(&t2[sp][cg * 8]);
        }
    } else {
        const int e = ((idx - 1024) * 256 + threadIdx.x) * 4;
        const float* src; int off; _Float16* d;
        if (e < 131072)      { src = qk; off = e;          d = wdst; }
        else if (e < 196608) { src = vs; off = e - 131072; d = wdst + 131072; }
        else                 { src = pj; off = e - 196608; d = wdst + 196608; }
        const float4 v = *(const float4*)(src + off);
        half4_t h; h[0] = (_Float16)v.x; h[1] = (_Float16)v.y; h[2] = (_Float16)v.z; h[3] = (_Float16)v.w;
        *(half4_t*)(d + off) = h;
    }
}

// ---- MFMA GEMM body: Out[o][col] = BN(sum_k W[o][k] * InT[col][k]) ----
// 128x128 tile, BK=64, 4 waves (2x2), 16x16x32 f16 MFMA.
// global_load_lds staging with source pre-swizzle: slot s = idx*8 + (kg ^ (idx&7)).
// OUT_T=1 (f16 [col][cout]): LDS-staged transposed epilogue. OUT_T=0 (f32 [b][o][sp]): direct.
template<int CIN, int NT, bool OUT_T>
__device__ __forceinline__
void gemm_body(int bid, int nblk, _Float16* As, _Float16* Bs, _Float16* sh,
               const _Float16* __restrict__ inH, const _Float16* __restrict__ wA,
               const float* __restrict__ bnp, void* __restrict__ outp, int cout)
{
    const int tid = threadIdx.x;
    const int lane = tid & 63;
    const int wv = tid >> 6;
    const int wm = wv >> 1, wn = wv & 1;
    const int grp = nblk >> 3;
    const int tile = (bid & 7) * grp + (bid >> 3);
    const int oBase = (tile % NT) * 128;
    const int colBase = (tile / NT) * 128;

    f32x4_t acc[4][4];
#pragma unroll
    for (int i = 0; i < 4; ++i)
#pragma unroll
        for (int j = 0; j < 4; ++j) acc[i][j] = (f32x4_t){0.f, 0.f, 0.f, 0.f};

    for (int k0 = 0; k0 < CIN; k0 += 64) {
        if (k0) __syncthreads();
#pragma unroll
        for (int it = 0; it < 4; ++it) {
            const int s = it * 256 + tid;
            const int sidx = s >> 3;
            const int skg = (s & 7) ^ (sidx & 7);   // inverse swizzle on global source
            gload16(wA + (long)(oBase + sidx) * CIN + k0 + skg * 8, As + s * 8);
            gload16(inH + (long)(colBase + sidx) * CIN + k0 + skg * 8, Bs + s * 8);
        }
        __syncthreads();
#pragma unroll
        for (int ks = 0; ks < 2; ++ks) {
            const int kq = ks * 4 + (lane >> 4);
            half8_t a[4], b[4];
#pragma unroll
            for (int mf = 0; mf < 4; ++mf) {
                const int idx = wm * 64 + mf * 16 + (lane & 15);
                a[mf] = *(const half8_t*)(As + (idx * 8 + (kq ^ (idx & 7))) * 8);
            }
#pragma unroll
            for (int nf = 0; nf < 4; ++nf) {
                const int idx = wn * 64 + nf * 16 + (lane & 15);
                b[nf] = *(const half8_t*)(Bs + (idx * 8 + (kq ^ (idx & 7))) * 8);
            }
#pragma unroll
            for (int mf = 0; mf < 4; ++mf)
#pragma unroll
                for (int nf = 0; nf < 4; ++nf)
                    acc[mf][nf] = __builtin_amdgcn_mfma_f32_16x16x32_f16(a[mf], b[nf], acc[mf][nf], 0, 0, 0);
        }
    }

    const int rbase = wm * 64 + (lane >> 4) * 4;
    if constexpr (OUT_T) {
        __syncthreads();   // all MFMA reads of As/Bs done before stage overwrite
#pragma unroll
        for (int mf = 0; mf < 4; ++mf) {
            const int ch0 = rbase + mf * 16;
            float inv[4], add[4];
#pragma unroll
            for (int j = 0; j < 4; ++j) bn_coef(bnp, cout, oBase + ch0 + j, inv[j], add[j]);
#pragma unroll
            for (int nf = 0; nf < 4; ++nf) {
                const int col_l = wn * 64 + nf * 16 + (lane & 15);
                half4_t v;
#pragma unroll
                for (int j = 0; j < 4; ++j) v[j] = (_Float16)(acc[mf][nf][j] * inv[j] + add[j]);
                *(half4_t*)(sh + col_l * 136 + ch0) = v;
            }
        }
        __syncthreads();
        for (int t = tid; t < 2048; t += 256) {
            const int col_l = t >> 4, chg = t & 15;
            _Float16* dst = (_Float16*)outp + (long)(colBase + col_l) * cout + oBase + chg * 8;
            *(half8_t*)dst = *(const half8_t*)(sh + col_l * 136 + chg * 8);
        }
    } else {
        const int cbase = colBase + wn * 64 + (lane & 15);
#pragma unroll
        for (int mf = 0; mf < 4; ++mf) {
            const int o0 = oBase + rbase + mf * 16;
            float inv[4], add[4];
#pragma unroll
            for (int j = 0; j < 4; ++j) bn_coef(bnp, cout, o0 + j, inv[j], add[j]);
#pragma unroll
            for (int nf = 0; nf < 4; ++nf) {
                const int col = cbase + nf * 16;
                const int bb = col / NSP, sp = col - bb * NSP;
                float* dst = (float*)outp + ((long)bb * cout + o0) * NSP + sp;
#pragma unroll
                for (int j = 0; j < 4; ++j) dst[(long)j * NSP] = acc[mf][nf][j] * inv[j] + add[j];
            }
        }
    }
}

// ---- vall body: per 128-col tile, prefix-sum x_t slices in f32 regs; per head MFMA with
//      W_h; LDS-staged epilogue -> concat_v [b][ch][sp] with 256B-contiguous sp-run writes. ----
__device__ __forceinline__
void vall_body(int bid, _Float16* As, _Float16* Bs, _Float16* sh,
               const _Float16* __restrict__ xt, const _Float16* __restrict__ vsw,
               const float* __restrict__ vsbn, _Float16* __restrict__ concat_v)
{
    const int tid = threadIdx.x, lane = tid & 63;
    const int wv = tid >> 6, wm = wv >> 1, wn = wv & 1;
    const int colBase = bid * 128;

    float bacc[4][8];
#pragma unroll
    for (int it = 0; it < 4; ++it)
#pragma unroll
        for (int j = 0; j < 8; ++j) bacc[it][j] = 0.f;

    for (int head = 0; head < NHEADS; ++head) {
        if (head) __syncthreads();   // also protects sh reads of previous epilogue
#pragma unroll
        for (int it = 0; it < 4; ++it) {
            const int c = it * 256 + tid;
            const int kg = c & 7, idx = c >> 3;
            const half8_t xv = *(const half8_t*)(xt + (long)(colBase + idx) * CDIM + head * 64 + kg * 8);
            half8_t bv;
#pragma unroll
            for (int j = 0; j < 8; ++j) { bacc[it][j] += (float)xv[j]; bv[j] = (_Float16)bacc[it][j]; }
            *(half8_t*)(Bs + (idx * 8 + (kg ^ (idx & 7))) * 8) = bv;   // swizzled slot
            const int skg = kg ^ (idx & 7);                            // inverse swizzle on source
            gload16(vsw + (long)head * (C4 * 64) + idx * 64 + skg * 8, As + c * 8);
        }
        __syncthreads();

        f32x4_t acc[4][4];
#pragma unroll
        for (int i = 0; i < 4; ++i)
#pragma unroll
            for (int j = 0; j < 4; ++j) acc[i][j] = (f32x4_t){0.f, 0.f, 0.f, 0.f};
#pragma unroll
        for (int ks = 0; ks < 2; ++ks) {
            const int kq = ks * 4 + (lane >> 4);
            half8_t a[4], b[4];
#pragma unroll
            for (int mf = 0; mf < 4; ++mf) {
                const int idx = wm * 64 + mf * 16 + (lane & 15);
                a[mf] = *(const half8_t*)(As + (idx * 8 + (kq ^ (idx & 7))) * 8);
            }
#pragma unroll
            for (int nf = 0; nf < 4; ++nf) {
                const int idx = wn * 64 + nf * 16 + (lane & 15);
                b[nf] = *(const half8_t*)(Bs + (idx * 8 + (kq ^ (idx & 7))) * 8);
            }
#pragma unroll
            for (int mf = 0; mf < 4; ++mf)
#pragma unroll
                for (int nf = 0; nf < 4; ++nf)
                    acc[mf][nf] = __builtin_amdgcn_mfma_f32_16x16x32_f16(a[mf], b[nf], acc[mf][nf], 0, 0, 0);
        }

        const int rbase = wm * 64 + (lane >> 4) * 4;
        const float* bnh = vsbn + head * 4 * C4;
        __syncthreads();   // MFMA reads done; sh (aliasing As/Bs) safe to overwrite
#pragma unroll
        for (int mf = 0; mf < 4; ++mf) {
            const int o0 = rbase + mf * 16;
            float inv[4], add[4];
#pragma unroll
            for (int j = 0; j < 4; ++j) bn_coef(bnh, C4, o0 + j, inv[j], add[j]);
#pragma unroll
            for (int nf = 0; nf < 4; ++nf) {
                const int col_l = wn * 64 + nf * 16 + (lane & 15);
#pragma unroll
                for (int j = 0; j < 4; ++j)
                    sh[(o0 + j) * 136 + col_l] = (_Float16)(acc[mf][nf][j] * inv[j] + add[j]);
            }
        }
        __syncthreads();
        for (int t = tid; t < 2048; t += 256) {
            const int ch = t >> 4, g = t & 15;
            const int col0 = colBase + g * 8;                 // 784 % 8 == 0: never straddles b
            const int bb = col0 / NSP, sp = col0 - bb * NSP;
            _Float16* dst = concat_v + ((long)bb * CCAT + head * C4 + ch) * NSP + sp;
            *(half8_t*)dst = *(const half8_t*)(sh + ch * 136 + g * 8);
        }
    }
}

// ---- merged launch: blocks 0..391 = vall (-> concat_v in d_out); 392..1175 = qk GEMM
//      (-> feat_t in ws). Disjoint buffers: race-free. ----
__global__ __launch_bounds__(256)
void qkvall_kernel(const _Float16* __restrict__ xt,
                   const _Float16* __restrict__ qkw, const float* __restrict__ qkbn,
                   _Float16* __restrict__ feat_t,
                   const _Float16* __restrict__ vsw, const float* __restrict__ vsbn,
                   _Float16* __restrict__ concat_v)
{
    __shared__ _Float16 sh[17408];   // As | Bs; epilogue stage [128][136] aliases (sync-separated)
    _Float16* As = sh;
    _Float16* Bs = sh + 8192;
    if (blockIdx.x < 392)
        vall_body(blockIdx.x, As, Bs, sh, xt, vsw, vsbn, concat_v);
    else
        gemm_body<CDIM, 2, true>(blockIdx.x - 392, 784, As, Bs, sh, xt, qkw, qkbn, feat_t, CQK);
}

// ---- standalone GEMM (proj) ----
template<int CIN, int NT, bool OUT_T>
__global__ __launch_bounds__(256)
void mfma_gemm_kernel(const _Float16* __restrict__ inH, const _Float16* __restrict__ wA,
                      const float* __restrict__ bnp, void* __restrict__ outp, int cout)
{
    __shared__ _Float16 sh[17408];
    gemm_body<CIN, NT, OUT_T>(blockIdx.x, gridDim.x, sh, sh + 8192, sh, inH, wA, bnp, outp, cout);
}

// ---- attention maps with fused depthwise conv + BN (both modes; blockIdx.z 0=row,1=col).
// Computes qdw inline from feat_t's q-half (halo in LDS), eliminating the qdw_t buffer:
//   rowmode (fix=h): Fs[dy][iw+2][c], qdw(h=fix, w=p, c) = sum wsh[c][dy,dx]*Fs[dy][p+dx][c]
//   colmode (fix=w): Fs[dx][ih+2][c], qdw(h=p, w=fix, c) = sum wsh[c][dy,dx]*Fs[dx][p+dy][c]
// Then S = Qs.Ks^T * scale + bias, softmax, padded f16 [b][28 fix][32 q][32 k] output.
__global__ __launch_bounds__(256)
void attn_map_dw_kernel(const _Float16* __restrict__ feat_t,
                        const float* __restrict__ dww, const float* __restrict__ dwbn,
                        const float* __restrict__ bias_w, const float* __restrict__ bias_h,
                        _Float16* __restrict__ attw_p, _Float16* __restrict__ atth_p)
{
    const int fix = blockIdx.x, b = blockIdx.y;
    const bool rowmode = (blockIdx.z == 0);
    const float* biasv = rowmode ? bias_w : bias_h;
    _Float16* attn_out = rowmode ? attw_p : atth_p;
    __shared__ _Float16 Fs[5 * 32 * 128];   // 40 KB halo tile, zero-padded borders
    __shared__ float wsh[128 * 26];         // dw weights, padded stride
    __shared__ _Float16 Qs[28][136];
    __shared__ _Float16 Ks[28][136];
    __shared__ float S[28][28];
    __shared__ float bsh[28];
    const int tid = threadIdx.x;
    if (tid < 28) bsh[tid] = biasv[tid];
    for (int i = tid; i < 128 * 25; i += 256) wsh[(i / 25) * 26 + (i % 25)] = dww[i];
    for (int i = tid; i < 2560; i += 256) {
        const int d1 = i >> 9;              // rowmode: dy ; colmode: dx
        const int rem = i & 511;
        const int r = rem >> 4;             // rowmode: iw+2 ; colmode: ih+2   (0..31)
        const int c8 = (rem & 15) * 8;
        int ih, iw;
        if (rowmode) { ih = fix + d1 - 2; iw = r - 2; }
        else         { ih = r - 2;        iw = fix + d1 - 2; }
        half8_t v = (half8_t){(_Float16)0.f, (_Float16)0.f, (_Float16)0.f, (_Float16)0.f,
                              (_Float16)0.f, (_Float16)0.f, (_Float16)0.f, (_Float16)0.f};
        if (ih >= 0 && ih < 28 && iw >= 0 && iw < 28)
            v = *(const half8_t*)(feat_t + ((long)b * NSP + ih * 28 + iw) * CQK + c8);
        *(half8_t*)(Fs + (d1 * 32 + r) * 128 + c8) = v;
    }
    for (int l = tid; l < 28 * 16; l += 256) {
        const int p = l >> 4, c8 = (l & 15) * 8;
        const int sp = rowmode ? (fix * 28 + p) : (p * 28 + fix);
        *(half8_t*)(&Ks[p][c8]) = *(const half8_t*)(feat_t + ((long)b * NSP + sp) * CQK + 128 + c8);
    }
    __syncthreads();
    // depthwise conv + BN -> Qs (c fixed per thread: stride 256 ≡ 0 mod 128)
    {
        const int c = tid & 127;
        float inv, add;
        bn_coef(dwbn, C4, c, inv, add);
        const float* wc = wsh + c * 26;
        if (rowmode) {
            for (int l = tid; l < 28 * 128; l += 256) {
                const int p = l >> 7;
                float acc = 0.f;
#pragma unroll
                for (int dy = 0; dy < 5; ++dy)
#pragma unroll
                    for (int dx = 0; dx < 5; ++dx)
                        acc = fmaf(wc[dy * 5 + dx], (float)Fs[(dy * 32 + p + dx) * 128 + c], acc);
                Qs[p][c] = (_Float16)(acc * inv + add);
            }
        } else {
            for (int l = tid; l < 28 * 128; l += 256) {
                const int p = l >> 7;
                float acc = 0.f;
#pragma unroll
                for (int dy = 0; dy < 5; ++dy)
#pragma unroll
                    for (int dx = 0; dx < 5; ++dx)
                        acc = fmaf(wc[dy * 5 + dx], (float)Fs[(dx * 32 + p + dy) * 128 + c], acc);
                Qs[p][c] = (_Float16)(acc * inv + add);
            }
        }
    }
    __syncthreads();
    for (int e = tid; e < 784; e += 256) {
        const int qp = e / 28, kp = e - (e / 28) * 28;
        float acc = 0.f;
        const half2_t* qv = (const half2_t*)&Qs[qp][0];
        const half2_t* kv = (const half2_t*)&Ks[kp][0];
#pragma unroll
        for (int c = 0; c < 64; ++c) acc = fdot2(qv[c], kv[c], acc);
        const int dd = qp - kp;
        S[qp][kp] = acc * ATT_SCALE + bsh[dd < 0 ? -dd : dd];
    }
    __syncthreads();
    const int r = tid >> 3, g = tid & 7;
    if (r < 28) {
        float mx = -1e30f;
#pragma unroll
        for (int j = 0; j < 4; ++j) { const int k = g + j * 8; if (k < 28) mx = fmaxf(mx, S[r][k]); }
        mx = fmaxf(mx, __shfl_xor(mx, 1));
        mx = fmaxf(mx, __shfl_xor(mx, 2));
        mx = fmaxf(mx, __shfl_xor(mx, 4));
        float e4[4], sum = 0.f;
#pragma unroll
        for (int j = 0; j < 4; ++j) {
            const int k = g + j * 8;
            e4[j] = (k < 28) ? __expf(S[r][k] - mx) : 0.f;
            sum += e4[j];
        }
        sum += __shfl_xor(sum, 1);
        sum += __shfl_xor(sum, 2);
        sum += __shfl_xor(sum, 4);
        const float rinv = 1.f / sum;
#pragma unroll
        for (int j = 0; j < 4; ++j) { const int k = g + j * 8; if (k < 28) S[r][k] = e4[j] * rinv; }
    }
    __syncthreads();
    _Float16* dst = attn_out + ((long)b * 28 + fix) * 1024;
    for (int i = tid; i < 1024; i += 256) {
        const int q = i >> 5, k = i & 31;
        dst[i] = (q < 28 && k < 28) ? (_Float16)S[q][k] : (_Float16)0.f;
    }
}

// ---- fused row+col attention apply + ReLU: concat_v [b][ch][sp] -> concat_out [b][sp][ch].
// Block = (b, dq-chunk of 16 ch) via XCD-swizzled 1D grid (4096 = 64 b x 64 dq).
// stage1 A (V^T rows, j contig) and B (attw rows) come DIRECTLY from global; only M1
// is staged in LDS ([w][17][42], odd strides). 40 KB LDS -> 4 blocks/CU.
__global__ __launch_bounds__(512)
void fused_stage_kernel(const _Float16* __restrict__ concat_v,
                        const _Float16* __restrict__ attw,
                        const _Float16* __restrict__ atth,
                        _Float16* __restrict__ concat_out)
{
    const int wgid = ((int)blockIdx.x & 7) * ((int)gridDim.x >> 3) + ((int)blockIdx.x >> 3);
    const int b = wgid >> 6, dq = wgid & 63;
    __shared__ _Float16 M1[28 * 17 * 42];   // [w][d(17)][r(42)]
    const int tid = threadIdx.x, lane = tid & 63, wv = tid >> 6;
    const int kg = lane >> 4, lr = lane & 15;

    const _Float16* vbase = concat_v + ((long)b * CCAT + dq * 16) * NSP;

    // zero M1 r-slots 28..31 (read by stage2's k range)
    for (int p = tid; p < 28 * 17 * 4; p += 512)
        M1[(p >> 2) * 42 + 28 + (p & 3)] = (_Float16)0.f;

    // stage 1: per row r: D1[d][w] = sum_j V^T[d][r*28+j] * attw[b,r][w][j]
    for (int r = wv; r < 28; r += 8) {
        const _Float16* bw = attw + ((long)b * 28 + r) * 1024;
        const long vrow = (long)lr * NSP + r * 28;
        half8_t a0;
        if (kg < 3) {
            a0 = *(const half8_t*)(vbase + vrow + kg * 8);
        } else {   // j = 24..27 valid (4 halves), j >= 28 padded 0 (attw cols are 0 there too)
            const half4_t lo = *(const half4_t*)(vbase + vrow + 24);
            a0 = (half8_t){lo[0], lo[1], lo[2], lo[3],
                           (_Float16)0.f, (_Float16)0.f, (_Float16)0.f, (_Float16)0.f};
        }
        const half8_t b0 = *(const half8_t*)(bw + lr * 32 + kg * 8);
        const half8_t b1 = *(const half8_t*)(bw + (16 + lr) * 32 + kg * 8);
        f32x4_t acc0 = (f32x4_t){0.f, 0.f, 0.f, 0.f};
        f32x4_t acc1 = (f32x4_t){0.f, 0.f, 0.f, 0.f};
        acc0 = __builtin_amdgcn_mfma_f32_16x16x32_f16(a0, b0, acc0, 0, 0, 0);
        acc1 = __builtin_amdgcn_mfma_f32_16x16x32_f16(a0, b1, acc1, 0, 0, 0);
        // D layout: d = kg*4+q (row), w = lr (col)
#pragma unroll
        for (int q = 0; q < 4; ++q) {
            const int d = kg * 4 + q;
            M1[(lr * 17 + d) * 42 + r] = (_Float16)acc0[q];
            if (16 + lr < 28) M1[((16 + lr) * 17 + d) * 42 + r] = (_Float16)acc1[q];
        }
    }
    __syncthreads();

    // stage 2: per col w: D2[d][h] = sum_k M1[w][d][k] * atth[b,w][h][k]; relu; write [sp][ch]
    _Float16* obase = concat_out + (long)b * NSP * CCAT + dq * 16;
    for (int w = wv; w < 28; w += 8) {
        const _Float16* bh = atth + ((long)b * 28 + w) * 1024;
        const half8_t a0 = *(const half8_t*)(M1 + (w * 17 + lr) * 42 + kg * 8);
        const half8_t b0 = *(const half8_t*)(bh + lr * 32 + kg * 8);
        const half8_t b1 = *(const half8_t*)(bh + (16 + lr) * 32 + kg * 8);
        f32x4_t acc0 = (f32x4_t){0.f, 0.f, 0.f, 0.f};
        f32x4_t acc1 = (f32x4_t){0.f, 0.f, 0.f, 0.f};
        acc0 = __builtin_amdgcn_mfma_f32_16x16x32_f16(a0, b0, acc0, 0, 0, 0);
        acc1 = __builtin_amdgcn_mfma_f32_16x16x32_f16(a0, b1, acc1, 0, 0, 0);
        const int d0 = kg * 4;
        {
            const int sp = lr * 28 + w;
            half4_t v;
#pragma unroll
            for (int q = 0; q < 4; ++q) v[q] = (_Float16)fmaxf(acc0[q], 0.f);
            *(half4_t*)(obase + (long)sp * CCAT + d0) = v;
        }
        if (16 + lr < 28) {
            const int sp = (16 + lr) * 28 + w;
            half4_t v;
#pragma unroll
            for (int q = 0; q < 4; ++q) v[q] = (_Float16)fmaxf(acc1[q], 0.f);
            *(half4_t*)(obase + (long)sp * CCAT + d0) = v;
        }
    }
}

extern "C" void kernel_launch(void* const* d_in, const int* in_sizes, int n_in,
                              void* d_out, int out_size, void* d_ws, size_t ws_size,
                              hipStream_t stream)
{
    const float* x        = (const float*)d_in[0];
    const float* qk_w     = (const float*)d_in[1];
    const float* qk_bn    = (const float*)d_in[2];
    const float* dws_w    = (const float*)d_in[3];
    const float* dws_bn   = (const float*)d_in[4];
    const float* vs_w     = (const float*)d_in[5];
    const float* vs_bn    = (const float*)d_in[6];
    const float* proj_w   = (const float*)d_in[7];
    const float* proj_bn  = (const float*)d_in[8];
    const float* bias_h   = (const float*)d_in[9];
    const float* bias_w   = (const float*)d_in[10];

    // --- ws layout (111.5 MB; feat in ws so qkvall's halves are race-free) ---
    char* wsb = (char*)d_ws;
    _Float16* x_t        = (_Float16*)wsb;               // [0, 51,380,224) dead after qkvall
    _Float16* feat_t     = (_Float16*)(wsb + 51380224);  // 25,690,112 -> 77,070,336, dead after attn_map
    _Float16* concat_out = (_Float16*)wsb;               // [0, 102,760,448) written by fused (x_t/feat dead)
    _Float16* attw_p     = (_Float16*)(wsb + 102760448); // 3,670,016
    _Float16* atth_p     = (_Float16*)(wsb + 106430464); // 3,670,016
    _Float16* w_h        = (_Float16*)(wsb + 110100480); // 1,441,792 -> 111,542,272
    _Float16* qk_w_h     = w_h;
    _Float16* vs_w_h     = w_h + 131072;
    _Float16* proj_w_h   = w_h + 196608;

    // --- d_out: concat_v [b][ch][sp] f16 (all of d_out); dead before proj writes f32 out ---
    _Float16* concat_v = (_Float16*)d_out;

    // merged transpose + weight convert
    prep_kernel<<<1728, 256, 0, stream>>>(x, x_t, qk_w, vs_w, proj_w, w_h);

    // merged: vall (blocks 0..391 -> concat_v in d_out) + qk GEMM (392..1175 -> feat_t in ws)
    qkvall_kernel<<<1176, 256, 0, stream>>>(
        x_t, qk_w_h, qk_bn, feat_t, vs_w_h, vs_bn, concat_v);

    // attention maps with fused depthwise conv (z = 0: row/bias_w, z = 1: col/bias_h)
    attn_map_dw_kernel<<<dim3(28, NB, 2), 256, 0, stream>>>(
        feat_t, dws_w, dws_bn, bias_w, bias_h, attw_p, atth_p);

    // fused row+col attention apply + relu: concat_v (d_out) -> concat_out (ws)
    fused_stage_kernel<<<4096, 512, 0, stream>>>(concat_v, attw_p, atth_p, concat_out);

    // out = BN(proj_w @ relu(concat)) ; reads ws, writes all of d_out (f32)
    mfma_gemm_kernel<CCAT, 4, false><<<1568, 256, 0, stream>>>(
        concat_out, proj_w_h, proj_bn, (float*)d_out, CDIM);
}

// Round 19
// 322.321 us; speedup vs baseline: 1.0214x; 1.0214x over previous
//
#include <hip/hip_runtime.h>
#include <hip/hip_fp16.h>

#define NB 64
#define NSP 784
#define CDIM 512
#define CQK 256
#define C4 128
#define NHEADS 8
#define CCAT 1024
#define BN_EPS 1e-5f
#define ATT_SCALE 0.17677669529663687f  // 32^-0.5

using half8_t = __attribute__((ext_vector_type(8))) _Float16;
using half4_t = __attribute__((ext_vector_type(4))) _Float16;
using half2_t = __attribute__((ext_vector_type(2))) _Float16;
using f32x4_t = __attribute__((ext_vector_type(4))) float;

__device__ __forceinline__ void bn_coef(const float* bn, int cout, int o, float& inv, float& add) {
    float g = bn[o], be = bn[cout + o], m = bn[2 * cout + o], v = bn[3 * cout + o];
    inv = g * rsqrtf(v + BN_EPS);
    add = be - m * inv;
}

__device__ __forceinline__ float fdot2(half2_t a, half2_t b, float c) {
#if __has_builtin(__builtin_amdgcn_fdot2)
    return __builtin_amdgcn_fdot2(a, b, c, false);
#else
    return c + (float)a[0] * (float)b[0] + (float)a[1] * (float)b[1];
#endif
}

// async global->LDS, 16B per lane; LDS dest must be wave-linear (base + lane*16).
__device__ __forceinline__ void gload16(const void* g, void* l) {
    __builtin_amdgcn_global_load_lds(
        (const __attribute__((address_space(1))) void*)g,
        (__attribute__((address_space(3))) void*)l, 16, 0, 0);
}

// ---- prep: merged x-transpose (blocks 0..1023) + weight convert (blocks 1024..1727) ----
__global__ __launch_bounds__(256)
void prep_kernel(const float* __restrict__ x, _Float16* __restrict__ xt,
                 const float* __restrict__ qk, const float* __restrict__ vs,
                 const float* __restrict__ pj, _Float16* __restrict__ wdst)
{
    __shared__ _Float16 t2[392][66];
    const int idx = blockIdx.x;
    if (idx < 1024) {
        const int c0 = (idx & 7) * 64, sp0 = ((idx >> 3) & 1) * 392, b = idx >> 4;
        const float* src = x + ((long)b * CDIM + c0) * NSP + sp0;
        for (int i = threadIdx.x; i < 64 * 392; i += 256) {
            const int c = i / 392, sp = i - c * 392;
            t2[sp][c] = (_Float16)src[(long)c * NSP + sp];
        }
        __syncthreads();
        _Float16* dst = xt + ((long)b * NSP + sp0) * CDIM + c0;
        for (int i = threadIdx.x; i < 392 * 8; i += 256) {
            const int sp = i >> 3, cg = i & 7;
            *(half8_t*)(dst + (long)sp * CDIM + cg * 8) = *(const half8_t*)(&t2[sp][cg * 8]);
        }
    } else {
        const int e = ((idx - 1024) * 256 + threadIdx.x) * 4;
        const float* src; int off; _Float16* d;
        if (e < 131072)      { src = qk; off = e;          d = wdst; }
        else if (e < 196608) { src = vs; off = e - 131072; d = wdst + 131072; }
        else                 { src = pj; off = e - 196608; d = wdst + 196608; }
        const float4 v = *(const float4*)(src + off);
        half4_t h; h[0] = (_Float16)v.x; h[1] = (_Float16)v.y; h[2] = (_Float16)v.z; h[3] = (_Float16)v.w;
        *(half4_t*)(d + off) = h;
    }
}

// ---- MFMA GEMM body: Out[o][col] = BN(sum_k W[o][k] * InT[col][k]) ----
// 128x128 tile, BK=64, 4 waves (2x2), 16x16x32 f16 MFMA.
// global_load_lds staging with source pre-swizzle: slot s = idx*8 + (kg ^ (idx&7)).
// OUT_T=1 (f16 [col][cout]): LDS-staged transposed epilogue. OUT_T=0 (f32 [b][o][sp]): direct.
template<int CIN, int NT, bool OUT_T>
__device__ __forceinline__
void gemm_body(int bid, int nblk, _Float16* As, _Float16* Bs, _Float16* sh,
               const _Float16* __restrict__ inH, const _Float16* __restrict__ wA,
               const float* __restrict__ bnp, void* __restrict__ outp, int cout)
{
    const int tid = threadIdx.x;
    const int lane = tid & 63;
    const int wv = tid >> 6;
    const int wm = wv >> 1, wn = wv & 1;
    const int grp = nblk >> 3;
    const int tile = (bid & 7) * grp + (bid >> 3);
    const int oBase = (tile % NT) * 128;
    const int colBase = (tile / NT) * 128;

    f32x4_t acc[4][4];
#pragma unroll
    for (int i = 0; i < 4; ++i)
#pragma unroll
        for (int j = 0; j < 4; ++j) acc[i][j] = (f32x4_t){0.f, 0.f, 0.f, 0.f};

    for (int k0 = 0; k0 < CIN; k0 += 64) {
        if (k0) __syncthreads();
#pragma unroll
        for (int it = 0; it < 4; ++it) {
            const int s = it * 256 + tid;
            const int sidx = s >> 3;
            const int skg = (s & 7) ^ (sidx & 7);   // inverse swizzle on global source
            gload16(wA + (long)(oBase + sidx) * CIN + k0 + skg * 8, As + s * 8);
            gload16(inH + (long)(colBase + sidx) * CIN + k0 + skg * 8, Bs + s * 8);
        }
        __syncthreads();
#pragma unroll
        for (int ks = 0; ks < 2; ++ks) {
            const int kq = ks * 4 + (lane >> 4);
            half8_t a[4], b[4];
#pragma unroll
            for (int mf = 0; mf < 4; ++mf) {
                const int idx = wm * 64 + mf * 16 + (lane & 15);
                a[mf] = *(const half8_t*)(As + (idx * 8 + (kq ^ (idx & 7))) * 8);
            }
#pragma unroll
            for (int nf = 0; nf < 4; ++nf) {
                const int idx = wn * 64 + nf * 16 + (lane & 15);
                b[nf] = *(const half8_t*)(Bs + (idx * 8 + (kq ^ (idx & 7))) * 8);
            }
#pragma unroll
            for (int mf = 0; mf < 4; ++mf)
#pragma unroll
                for (int nf = 0; nf < 4; ++nf)
                    acc[mf][nf] = __builtin_amdgcn_mfma_f32_16x16x32_f16(a[mf], b[nf], acc[mf][nf], 0, 0, 0);
        }
    }

    const int rbase = wm * 64 + (lane >> 4) * 4;
    if constexpr (OUT_T) {
        __syncthreads();   // all MFMA reads of As/Bs done before stage overwrite
#pragma unroll
        for (int mf = 0; mf < 4; ++mf) {
            const int ch0 = rbase + mf * 16;
            float inv[4], add[4];
#pragma unroll
            for (int j = 0; j < 4; ++j) bn_coef(bnp, cout, oBase + ch0 + j, inv[j], add[j]);
#pragma unroll
            for (int nf = 0; nf < 4; ++nf) {
                const int col_l = wn * 64 + nf * 16 + (lane & 15);
                half4_t v;
#pragma unroll
                for (int j = 0; j < 4; ++j) v[j] = (_Float16)(acc[mf][nf][j] * inv[j] + add[j]);
                *(half4_t*)(sh + col_l * 136 + ch0) = v;
            }
        }
        __syncthreads();
        for (int t = tid; t < 2048; t += 256) {
            const int col_l = t >> 4, chg = t & 15;
            _Float16* dst = (_Float16*)outp + (long)(colBase + col_l) * cout + oBase + chg * 8;
            *(half8_t*)dst = *(const half8_t*)(sh + col_l * 136 + chg * 8);
        }
    } else {
        const int cbase = colBase + wn * 64 + (lane & 15);
#pragma unroll
        for (int mf = 0; mf < 4; ++mf) {
            const int o0 = oBase + rbase + mf * 16;
            float inv[4], add[4];
#pragma unroll
            for (int j = 0; j < 4; ++j) bn_coef(bnp, cout, o0 + j, inv[j], add[j]);
#pragma unroll
            for (int nf = 0; nf < 4; ++nf) {
                const int col = cbase + nf * 16;
                const int bb = col / NSP, sp = col - bb * NSP;
                float* dst = (float*)outp + ((long)bb * cout + o0) * NSP + sp;
#pragma unroll
                for (int j = 0; j < 4; ++j) dst[(long)j * NSP] = acc[mf][nf][j] * inv[j] + add[j];
            }
        }
    }
}

// ---- vall body: per 128-col tile, prefix-sum x_t slices in f32 regs; per head MFMA with
//      W_h; LDS-staged epilogue -> concat_v [b][ch][sp] with 256B-contiguous sp-run writes. ----
__device__ __forceinline__
void vall_body(int bid, _Float16* As, _Float16* Bs, _Float16* sh,
               const _Float16* __restrict__ xt, const _Float16* __restrict__ vsw,
               const float* __restrict__ vsbn, _Float16* __restrict__ concat_v)
{
    const int tid = threadIdx.x, lane = tid & 63;
    const int wv = tid >> 6, wm = wv >> 1, wn = wv & 1;
    const int colBase = bid * 128;

    float bacc[4][8];
#pragma unroll
    for (int it = 0; it < 4; ++it)
#pragma unroll
        for (int j = 0; j < 8; ++j) bacc[it][j] = 0.f;

    for (int head = 0; head < NHEADS; ++head) {
        if (head) __syncthreads();   // also protects sh reads of previous epilogue
#pragma unroll
        for (int it = 0; it < 4; ++it) {
            const int c = it * 256 + tid;
            const int kg = c & 7, idx = c >> 3;
            const half8_t xv = *(const half8_t*)(xt + (long)(colBase + idx) * CDIM + head * 64 + kg * 8);
            half8_t bv;
#pragma unroll
            for (int j = 0; j < 8; ++j) { bacc[it][j] += (float)xv[j]; bv[j] = (_Float16)bacc[it][j]; }
            *(half8_t*)(Bs + (idx * 8 + (kg ^ (idx & 7))) * 8) = bv;   // swizzled slot
            const int skg = kg ^ (idx & 7);                            // inverse swizzle on source
            gload16(vsw + (long)head * (C4 * 64) + idx * 64 + skg * 8, As + c * 8);
        }
        __syncthreads();

        f32x4_t acc[4][4];
#pragma unroll
        for (int i = 0; i < 4; ++i)
#pragma unroll
            for (int j = 0; j < 4; ++j) acc[i][j] = (f32x4_t){0.f, 0.f, 0.f, 0.f};
#pragma unroll
        for (int ks = 0; ks < 2; ++ks) {
            const int kq = ks * 4 + (lane >> 4);
            half8_t a[4], b[4];
#pragma unroll
            for (int mf = 0; mf < 4; ++mf) {
                const int idx = wm * 64 + mf * 16 + (lane & 15);
                a[mf] = *(const half8_t*)(As + (idx * 8 + (kq ^ (idx & 7))) * 8);
            }
#pragma unroll
            for (int nf = 0; nf < 4; ++nf) {
                const int idx = wn * 64 + nf * 16 + (lane & 15);
                b[nf] = *(const half8_t*)(Bs + (idx * 8 + (kq ^ (idx & 7))) * 8);
            }
#pragma unroll
            for (int mf = 0; mf < 4; ++mf)
#pragma unroll
                for (int nf = 0; nf < 4; ++nf)
                    acc[mf][nf] = __builtin_amdgcn_mfma_f32_16x16x32_f16(a[mf], b[nf], acc[mf][nf], 0, 0, 0);
        }

        const int rbase = wm * 64 + (lane >> 4) * 4;
        const float* bnh = vsbn + head * 4 * C4;
        __syncthreads();   // MFMA reads done; sh (aliasing As/Bs) safe to overwrite
#pragma unroll
        for (int mf = 0; mf < 4; ++mf) {
            const int o0 = rbase + mf * 16;
            float inv[4], add[4];
#pragma unroll
            for (int j = 0; j < 4; ++j) bn_coef(bnh, C4, o0 + j, inv[j], add[j]);
#pragma unroll
            for (int nf = 0; nf < 4; ++nf) {
                const int col_l = wn * 64 + nf * 16 + (lane & 15);
#pragma unroll
                for (int j = 0; j < 4; ++j)
                    sh[(o0 + j) * 136 + col_l] = (_Float16)(acc[mf][nf][j] * inv[j] + add[j]);
            }
        }
        __syncthreads();
        for (int t = tid; t < 2048; t += 256) {
            const int ch = t >> 4, g = t & 15;
            const int col0 = colBase + g * 8;                 // 784 % 8 == 0: never straddles b
            const int bb = col0 / NSP, sp = col0 - bb * NSP;
            _Float16* dst = concat_v + ((long)bb * CCAT + head * C4 + ch) * NSP + sp;
            *(half8_t*)dst = *(const half8_t*)(sh + ch * 136 + g * 8);
        }
    }
}

// ---- merged launch: blocks 0..391 = vall (-> concat_v in d_out); 392..1175 = qk GEMM
//      (-> feat_t in ws). Disjoint buffers: race-free. ----
__global__ __launch_bounds__(256)
void qkvall_kernel(const _Float16* __restrict__ xt,
                   const _Float16* __restrict__ qkw, const float* __restrict__ qkbn,
                   _Float16* __restrict__ feat_t,
                   const _Float16* __restrict__ vsw, const float* __restrict__ vsbn,
                   _Float16* __restrict__ concat_v)
{
    __shared__ _Float16 sh[17408];   // As | Bs; epilogue stage [128][136] aliases (sync-separated)
    _Float16* As = sh;
    _Float16* Bs = sh + 8192;
    if (blockIdx.x < 392)
        vall_body(blockIdx.x, As, Bs, sh, xt, vsw, vsbn, concat_v);
    else
        gemm_body<CDIM, 2, true>(blockIdx.x - 392, 784, As, Bs, sh, xt, qkw, qkbn, feat_t, CQK);
}

// ---- standalone GEMM (proj) ----
template<int CIN, int NT, bool OUT_T>
__global__ __launch_bounds__(256)
void mfma_gemm_kernel(const _Float16* __restrict__ inH, const _Float16* __restrict__ wA,
                      const float* __restrict__ bnp, void* __restrict__ outp, int cout)
{
    __shared__ _Float16 sh[17408];
    gemm_body<CIN, NT, OUT_T>(blockIdx.x, gridDim.x, sh, sh + 8192, sh, inH, wA, bnp, outp, cout);
}

// ---- depthwise 5x5 SAME + BN; feat_t [sp][256] (q = c<128) -> qdw_t [sp][128] ----
__global__ __launch_bounds__(256)
void dwconv_t_kernel(const _Float16* __restrict__ feat_t, const float* __restrict__ dww,
                     const float* __restrict__ dwbn, _Float16* __restrict__ qdw_t)
{
    const int h = blockIdx.x, b = blockIdx.y, ch0 = blockIdx.z * 64;
    __shared__ _Float16 rows[5][32][64];  // [dy][iw+2][c], borders zero
    for (int i = threadIdx.x; i < 5 * 32 * 64; i += 256) {
        const int dy = i / (32 * 64);
        const int rem = i - dy * (32 * 64);
        const int iw = rem >> 6, c = rem & 63;
        const int ih = h + dy - 2, w = iw - 2;
        _Float16 v = (_Float16)0.f;
        if (ih >= 0 && ih < 28 && w >= 0 && w < 28)
            v = feat_t[((long)b * NSP + ih * 28 + w) * CQK + ch0 + c];
        rows[dy][iw][c] = v;
    }
    const int pr = threadIdx.x & 31;
    const int c2 = pr * 2;
    float wr0[25], wr1[25];
#pragma unroll
    for (int q = 0; q < 25; ++q) {
        wr0[q] = dww[(ch0 + c2) * 25 + q];
        wr1[q] = dww[(ch0 + c2 + 1) * 25 + q];
    }
    float inv0, add0, inv1, add1;
    bn_coef(dwbn, C4, ch0 + c2, inv0, add0);
    bn_coef(dwbn, C4, ch0 + c2 + 1, inv1, add1);
    __syncthreads();
    for (int l = threadIdx.x; l < 28 * 32; l += 256) {
        const int w = l >> 5;
        float a0 = 0.f, a1 = 0.f;
#pragma unroll
        for (int dy = 0; dy < 5; ++dy)
#pragma unroll
            for (int dx = 0; dx < 5; ++dx) {
                const half2_t v2 = *(const half2_t*)(&rows[dy][w + dx][c2]);
                a0 += wr0[dy * 5 + dx] * (float)v2[0];
                a1 += wr1[dy * 5 + dx] * (float)v2[1];
            }
        half2_t o2; o2[0] = (_Float16)(a0 * inv0 + add0); o2[1] = (_Float16)(a1 * inv1 + add1);
        *(half2_t*)(qdw_t + ((long)b * NSP + h * 28 + w) * C4 + ch0 + c2) = o2;
    }
}

// ---- attention maps (both modes in one launch; blockIdx.z: 0=row/bias_w, 1=col/bias_h)
//      -> padded f16 [b][28 fix][32 q][32 k], zero-filled pads. ----
__global__ __launch_bounds__(256)
void attn_map_kernel(const _Float16* __restrict__ qdw_t, const _Float16* __restrict__ feat_t,
                     const float* __restrict__ bias_w, const float* __restrict__ bias_h,
                     _Float16* __restrict__ attw_p, _Float16* __restrict__ atth_p)
{
    const int fix = blockIdx.x, b = blockIdx.y;
    const bool rowmode = (blockIdx.z == 0);
    const float* biasv = rowmode ? bias_w : bias_h;
    _Float16* attn_out = rowmode ? attw_p : atth_p;
    __shared__ _Float16 Qs[28][136];
    __shared__ _Float16 Ks[28][136];
    __shared__ float S[28][28];
    __shared__ float bsh[28];
    if (threadIdx.x < 28) bsh[threadIdx.x] = biasv[threadIdx.x];
    for (int l = threadIdx.x; l < 28 * 16; l += 256) {
        const int p = l >> 4, c8 = (l & 15) * 8;
        const int sp = rowmode ? (fix * 28 + p) : (p * 28 + fix);
        *(half8_t*)(&Qs[p][c8]) = *(const half8_t*)(qdw_t + ((long)b * NSP + sp) * C4 + c8);
        *(half8_t*)(&Ks[p][c8]) = *(const half8_t*)(feat_t + ((long)b * NSP + sp) * CQK + 128 + c8);
    }
    __syncthreads();
    for (int e = threadIdx.x; e < 784; e += 256) {
        const int qp = e / 28, kp = e - (e / 28) * 28;
        float acc = 0.f;
        const half2_t* qv = (const half2_t*)&Qs[qp][0];
        const half2_t* kv = (const half2_t*)&Ks[kp][0];
#pragma unroll
        for (int c = 0; c < 64; ++c) acc = fdot2(qv[c], kv[c], acc);
        const int dd = qp - kp;
        S[qp][kp] = acc * ATT_SCALE + bsh[dd < 0 ? -dd : dd];
    }
    __syncthreads();
    const int r = threadIdx.x >> 3, g = threadIdx.x & 7;
    if (r < 28) {
        float mx = -1e30f;
#pragma unroll
        for (int j = 0; j < 4; ++j) { const int k = g + j * 8; if (k < 28) mx = fmaxf(mx, S[r][k]); }
        mx = fmaxf(mx, __shfl_xor(mx, 1));
        mx = fmaxf(mx, __shfl_xor(mx, 2));
        mx = fmaxf(mx, __shfl_xor(mx, 4));
        float e4[4], sum = 0.f;
#pragma unroll
        for (int j = 0; j < 4; ++j) {
            const int k = g + j * 8;
            e4[j] = (k < 28) ? __expf(S[r][k] - mx) : 0.f;
            sum += e4[j];
        }
        sum += __shfl_xor(sum, 1);
        sum += __shfl_xor(sum, 2);
        sum += __shfl_xor(sum, 4);
        const float rinv = 1.f / sum;
#pragma unroll
        for (int j = 0; j < 4; ++j) { const int k = g + j * 8; if (k < 28) S[r][k] = e4[j] * rinv; }
    }
    __syncthreads();
    _Float16* dst = attn_out + ((long)b * 28 + fix) * 1024;
    for (int i = threadIdx.x; i < 1024; i += 256) {
        const int q = i >> 5, k = i & 31;
        dst[i] = (q < 28 && k < 28) ? (_Float16)S[q][k] : (_Float16)0.f;
    }
}

// ---- fused row+col attention apply + ReLU: concat_v [b][ch][sp] -> concat_out [b][sp][ch].
// Block = (b, dq-chunk of 16 ch) via XCD-swizzled 1D grid (4096 = 64 b x 64 dq).
// stage1 A (V^T rows, j contig) and B (attw rows) come DIRECTLY from global; only M1
// is staged in LDS ([w][17][42], odd strides). 40 KB LDS -> 4 blocks/CU.
__global__ __launch_bounds__(512)
void fused_stage_kernel(const _Float16* __restrict__ concat_v,
                        const _Float16* __restrict__ attw,
                        const _Float16* __restrict__ atth,
                        _Float16* __restrict__ concat_out)
{
    const int wgid = ((int)blockIdx.x & 7) * ((int)gridDim.x >> 3) + ((int)blockIdx.x >> 3);
    const int b = wgid >> 6, dq = wgid & 63;
    __shared__ _Float16 M1[28 * 17 * 42];   // [w][d(17)][r(42)]
    const int tid = threadIdx.x, lane = tid & 63, wv = tid >> 6;
    const int kg = lane >> 4, lr = lane & 15;

    const _Float16* vbase = concat_v + ((long)b * CCAT + dq * 16) * NSP;

    // zero M1 r-slots 28..31 (read by stage2's k range)
    for (int p = tid; p < 28 * 17 * 4; p += 512)
        M1[(p >> 2) * 42 + 28 + (p & 3)] = (_Float16)0.f;

    // stage 1: per row r: D1[d][w] = sum_j V^T[d][r*28+j] * attw[b,r][w][j]
    for (int r = wv; r < 28; r += 8) {
        const _Float16* bw = attw + ((long)b * 28 + r) * 1024;
        const long vrow = (long)lr * NSP + r * 28;
        half8_t a0;
        if (kg < 3) {
            a0 = *(const half8_t*)(vbase + vrow + kg * 8);
        } else {   // j = 24..27 valid (4 halves), j >= 28 padded 0 (attw cols are 0 there too)
            const half4_t lo = *(const half4_t*)(vbase + vrow + 24);
            a0 = (half8_t){lo[0], lo[1], lo[2], lo[3],
                           (_Float16)0.f, (_Float16)0.f, (_Float16)0.f, (_Float16)0.f};
        }
        const half8_t b0 = *(const half8_t*)(bw + lr * 32 + kg * 8);
        const half8_t b1 = *(const half8_t*)(bw + (16 + lr) * 32 + kg * 8);
        f32x4_t acc0 = (f32x4_t){0.f, 0.f, 0.f, 0.f};
        f32x4_t acc1 = (f32x4_t){0.f, 0.f, 0.f, 0.f};
        acc0 = __builtin_amdgcn_mfma_f32_16x16x32_f16(a0, b0, acc0, 0, 0, 0);
        acc1 = __builtin_amdgcn_mfma_f32_16x16x32_f16(a0, b1, acc1, 0, 0, 0);
        // D layout: d = kg*4+q (row), w = lr (col)
#pragma unroll
        for (int q = 0; q < 4; ++q) {
            const int d = kg * 4 + q;
            M1[(lr * 17 + d) * 42 + r] = (_Float16)acc0[q];
            if (16 + lr < 28) M1[((16 + lr) * 17 + d) * 42 + r] = (_Float16)acc1[q];
        }
    }
    __syncthreads();

    // stage 2: per col w: D2[d][h] = sum_k M1[w][d][k] * atth[b,w][h][k]; relu; write [sp][ch]
    _Float16* obase = concat_out + (long)b * NSP * CCAT + dq * 16;
    for (int w = wv; w < 28; w += 8) {
        const _Float16* bh = atth + ((long)b * 28 + w) * 1024;
        const half8_t a0 = *(const half8_t*)(M1 + (w * 17 + lr) * 42 + kg * 8);
        const half8_t b0 = *(const half8_t*)(bh + lr * 32 + kg * 8);
        const half8_t b1 = *(const half8_t*)(bh + (16 + lr) * 32 + kg * 8);
        f32x4_t acc0 = (f32x4_t){0.f, 0.f, 0.f, 0.f};
        f32x4_t acc1 = (f32x4_t){0.f, 0.f, 0.f, 0.f};
        acc0 = __builtin_amdgcn_mfma_f32_16x16x32_f16(a0, b0, acc0, 0, 0, 0);
        acc1 = __builtin_amdgcn_mfma_f32_16x16x32_f16(a0, b1, acc1, 0, 0, 0);
        const int d0 = kg * 4;
        {
            const int sp = lr * 28 + w;
            half4_t v;
#pragma unroll
            for (int q = 0; q < 4; ++q) v[q] = (_Float16)fmaxf(acc0[q], 0.f);
            *(half4_t*)(obase + (long)sp * CCAT + d0) = v;
        }
        if (16 + lr < 28) {
            const int sp = (16 + lr) * 28 + w;
            half4_t v;
#pragma unroll
            for (int q = 0; q < 4; ++q) v[q] = (_Float16)fmaxf(acc1[q], 0.f);
            *(half4_t*)(obase + (long)sp * CCAT + d0) = v;
        }
    }
}

extern "C" void kernel_launch(void* const* d_in, const int* in_sizes, int n_in,
                              void* d_out, int out_size, void* d_ws, size_t ws_size,
                              hipStream_t stream)
{
    const float* x        = (const float*)d_in[0];
    const float* qk_w     = (const float*)d_in[1];
    const float* qk_bn    = (const float*)d_in[2];
    const float* dws_w    = (const float*)d_in[3];
    const float* dws_bn   = (const float*)d_in[4];
    const float* vs_w     = (const float*)d_in[5];
    const float* vs_bn    = (const float*)d_in[6];
    const float* proj_w   = (const float*)d_in[7];
    const float* proj_bn  = (const float*)d_in[8];
    const float* bias_h   = (const float*)d_in[9];
    const float* bias_w   = (const float*)d_in[10];

    // --- ws layout (111.5 MB; feat/qdw in ws so qkvall's halves are race-free) ---
    char* wsb = (char*)d_ws;
    _Float16* x_t        = (_Float16*)wsb;               // [0, 51,380,224) dead after qkvall
    _Float16* feat_t     = (_Float16*)(wsb + 51380224);  // 25,690,112 -> 77,070,336, dead after attn_map
    _Float16* qdw_t      = (_Float16*)(wsb + 77070336);  // 12,845,056 -> 89,915,392, dead after attn_map
    _Float16* concat_out = (_Float16*)wsb;               // [0, 102,760,448) written by fused (x_t/feat/qdw dead)
    _Float16* attw_p     = (_Float16*)(wsb + 102760448); // 3,670,016
    _Float16* atth_p     = (_Float16*)(wsb + 106430464); // 3,670,016
    _Float16* w_h        = (_Float16*)(wsb + 110100480); // 1,441,792 -> 111,542,272
    _Float16* qk_w_h     = w_h;
    _Float16* vs_w_h     = w_h + 131072;
    _Float16* proj_w_h   = w_h + 196608;

    // --- d_out: concat_v [b][ch][sp] f16 (all of d_out); dead before proj writes f32 out ---
    _Float16* concat_v = (_Float16*)d_out;

    // merged transpose + weight convert
    prep_kernel<<<1728, 256, 0, stream>>>(x, x_t, qk_w, vs_w, proj_w, w_h);

    // merged: vall (blocks 0..391 -> concat_v in d_out) + qk GEMM (392..1175 -> feat_t in ws)
    qkvall_kernel<<<1176, 256, 0, stream>>>(
        x_t, qk_w_h, qk_bn, feat_t, vs_w_h, vs_bn, concat_v);

    dwconv_t_kernel<<<dim3(28, NB, 2), 256, 0, stream>>>(feat_t, dws_w, dws_bn, qdw_t);

    // both attention maps in one launch (z = 0: row/bias_w -> attw, z = 1: col/bias_h -> atth)
    attn_map_kernel<<<dim3(28, NB, 2), 256, 0, stream>>>(
        qdw_t, feat_t, bias_w, bias_h, attw_p, atth_p);

    // fused row+col attention apply + relu: concat_v (d_out) -> concat_out (ws)
    fused_stage_kernel<<<4096, 512, 0, stream>>>(concat_v, attw_p, atth_p, concat_out);

    // out = BN(proj_w @ relu(concat)) ; reads ws, writes all of d_out (f32)
    mfma_gemm_kernel<CCAT, 4, false><<<1568, 256, 0, stream>>>(
        concat_out, proj_w_h, proj_bn, (float*)d_out, CDIM);
}